// Round 1
// baseline (25.264 us; speedup 1.0000x reference)
//
#include <hip/hip_runtime.h>

typedef int int4v __attribute__((ext_vector_type(4)));

// Streaming kernel:
//  region [0, n_tok_vec)            : tokens -> pad-replace -> count-mask -> out
//  region [n_tok_vec, +n_cnt_vec)   : counts passthrough copy
__global__ __launch_bounds__(256) void FusedSpeculativeBase_kernel(
    const int* __restrict__ tokens,   // [B*K] int32
    const int* __restrict__ counts,   // [B]   int32
    const int* __restrict__ pad_ptr,  // [1]   int32
    int* __restrict__ out,            // [B*K + B] int32
    int n_tok_vec,                    // B*K/4
    int n_cnt_vec,                    // B/4
    int row_shift)                    // log2(K/4)
{
    const int pad = pad_ptr[0];
    const int npv = tokens[0];        // non_pad_value = tokens[0,0] (pre-replacement)
    const int vecs_per_row_mask = (1 << row_shift) - 1;
    const int total = n_tok_vec + n_cnt_vec;
    const int stride = gridDim.x * blockDim.x;

    for (int idx = blockIdx.x * blockDim.x + threadIdx.x; idx < total; idx += stride) {
        if (idx < n_tok_vec) {
            const int4v v = ((const int4v*)tokens)[idx];
            const int row = idx >> row_shift;
            const int p0  = (idx & vecs_per_row_mask) << 2;  // starting token pos in row
            const int cnt = counts[row];                     // broadcast across 2^row_shift lanes
            int4v r;
#pragma unroll
            for (int j = 0; j < 4; ++j) {
                int t = v[j];
                t = (t == pad) ? npv : t;                    // pad replacement
                r[j] = ((p0 + j) < cnt) ? t : pad;           // keep-first-cnt mask
            }
            ((int4v*)out)[idx] = r;
        } else {
            const int c = idx - n_tok_vec;
            int4v* out_cnt = (int4v*)(out + ((size_t)n_tok_vec << 2));
            out_cnt[c] = ((const int4v*)counts)[c];
        }
    }
}

extern "C" void kernel_launch(void* const* d_in, const int* in_sizes, int n_in,
                              void* d_out, int out_size, void* d_ws, size_t ws_size,
                              hipStream_t stream) {
    const int* tokens  = (const int*)d_in[0];
    const int* counts  = (const int*)d_in[1];
    const int* pad_ptr = (const int*)d_in[2];
    int* out = (int*)d_out;

    const int n_tok = in_sizes[0];      // B*K
    const int n_b   = in_sizes[1];      // B
    const int K     = n_tok / n_b;      // 64
    const int vecs_per_row = K / 4;     // 16 (power of two)
    int row_shift = 0;
    while ((1 << row_shift) < vecs_per_row) ++row_shift;

    const int n_tok_vec = n_tok / 4;
    const int n_cnt_vec = n_b / 4;
    const int total = n_tok_vec + n_cnt_vec;

    const int block = 256;
    int grid = (total + block - 1) / block;
    if (grid > 2048) grid = 2048;

    FusedSpeculativeBase_kernel<<<grid, block, 0, stream>>>(
        tokens, counts, pad_ptr, out, n_tok_vec, n_cnt_vec, row_shift);
}